// Round 1
// 1970.652 us; speedup vs baseline: 1.0544x; 1.0544x over previous
//
#include <hip/hip_runtime.h>
#include <math.h>

#define TT 2048
#define EE 768
#define HNN 12
#define HSS 64
#define NLAYER 6
#define FFD 3072
#define QKVN 2304

constexpr float LN_EPS = 1e-5f;
constexpr float ATT_SCALE = 0.03608439182435161f; // 1/sqrt(768) (reference divides by sqrt(n_embed))

typedef __attribute__((ext_vector_type(8))) short bf16x8;
typedef __attribute__((ext_vector_type(4))) float f32x4;

__device__ __forceinline__ ushort f2bf(float f) {
    union { float f; uint u; } c; c.f = f;
    const uint u = c.u;
    return (ushort)((u + 0x7fffu + ((u >> 16) & 1u)) >> 16);
}

__device__ __forceinline__ void gload16(const void* g, void* l) {
    __builtin_amdgcn_global_load_lds((const __attribute__((address_space(1))) void*)g,
                                     (__attribute__((address_space(3))) void*)l, 16, 0, 0);
}

// ---------------------------------------------------------------- copy ----
__global__ __launch_bounds__(256) void copy4_kernel(float4* __restrict__ dst,
                                                    const float4* __restrict__ src, int n4) {
    int i = blockIdx.x * 256 + threadIdx.x;
    if (i < n4) dst[i] = src[i];
}

// ----------------------------------------------------------- layernorm ----
// one block (256 thr) per token; E=768 = 3*256.  fp32 in -> bf16 out.
__global__ __launch_bounds__(256) void ln_kernel(const float* __restrict__ in,
                                                 const float* __restrict__ g,
                                                 const float* __restrict__ b,
                                                 ushort* __restrict__ out) {
    __shared__ float red[8];
    const int t = blockIdx.x;
    const int tid = threadIdx.x;
    const float* row = in + (size_t)t * EE;
    float v0 = row[tid], v1 = row[tid + 256], v2 = row[tid + 512];
    float s = v0 + v1 + v2;
#pragma unroll
    for (int m = 1; m < 64; m <<= 1) s += __shfl_xor(s, m, 64);
    if ((tid & 63) == 0) red[tid >> 6] = s;
    __syncthreads();
    const float mean = (red[0] + red[1] + red[2] + red[3]) * (1.0f / EE);
    const float d0 = v0 - mean, d1 = v1 - mean, d2 = v2 - mean;
    float qq = d0 * d0 + d1 * d1 + d2 * d2;
#pragma unroll
    for (int m = 1; m < 64; m <<= 1) qq += __shfl_xor(qq, m, 64);
    __syncthreads();
    if ((tid & 63) == 0) red[tid >> 6] = qq;
    __syncthreads();
    const float var = (red[0] + red[1] + red[2] + red[3]) * (1.0f / EE);
    const float rstd = rsqrtf(var + LN_EPS);
    ushort* orow = out + (size_t)t * EE;
    orow[tid]       = f2bf(d0 * rstd * g[tid]       + b[tid]);
    orow[tid + 256] = f2bf(d1 * rstd * g[tid + 256] + b[tid + 256]);
    orow[tid + 512] = f2bf(d2 * rstd * g[tid + 512] + b[tid + 512]);
}

// --------------------------------------------------- weight pack (fp32->bf16^T)
// dst[n][k] (bf16, row stride dld) = src[k][n] (fp32, row stride sld), 64x64 tile
__device__ __forceinline__ void transpose64(const float* __restrict__ src, int sld,
                                            ushort* __restrict__ dst, int dld,
                                            int k0, int n0, int tid) {
    __shared__ float t[64][68];
#pragma unroll
    for (int p = 0; p < 4; p++) {
        const int kr = p * 16 + (tid >> 4);
        *(float4*)&t[kr][(tid & 15) * 4] =
            *(const float4*)&src[(size_t)(k0 + kr) * sld + n0 + (tid & 15) * 4];
    }
    __syncthreads();
#pragma unroll
    for (int q = 0; q < 2; q++) {
        const int nl = q * 32 + (tid >> 3);
        const int kc = (tid & 7) * 8;
        ushort v[8];
#pragma unroll
        for (int j = 0; j < 8; j++) v[j] = f2bf(t[kc + j][nl]);
        uint4 o;
        o.x = (uint)v[0] | ((uint)v[1] << 16);
        o.y = (uint)v[2] | ((uint)v[3] << 16);
        o.z = (uint)v[4] | ((uint)v[5] << 16);
        o.w = (uint)v[6] | ((uint)v[7] << 16);
        *(uint4*)&dst[(size_t)(n0 + nl) * dld + k0 + kc] = o;
    }
}

__global__ __launch_bounds__(256) void pack_t_kernel(const float* __restrict__ src, int sld,
                                                     ushort* __restrict__ dst, int dld) {
    transpose64(src, sld, dst, dld, blockIdx.x * 64, blockIdx.y * 64, threadIdx.x);
}

// qkv weights [HN][E][HS] (3 tensors) -> Wqkv_t[2304][768] bf16 (row n = which*768+h*64+s)
__global__ __launch_bounds__(256) void pack_qkv_kernel(const float* __restrict__ wq,
                                                       const float* __restrict__ wk,
                                                       const float* __restrict__ wv,
                                                       ushort* __restrict__ dst) {
    const int z = blockIdx.z;
    const int which = z / HNN, hd = z % HNN;
    const float* src = (which == 0 ? wq : which == 1 ? wk : wv) + (size_t)hd * EE * HSS;
    ushort* d = dst + (size_t)(which * EE + hd * HSS) * EE;
    transpose64(src, HSS, d, EE, blockIdx.x * 64, 0, threadIdx.x);
}

// ---------------------------------------------------------- bf16 GEMM ----
// C[M,N] = epi(A[M,K] @ Bt[N,K]^T + bias).  128x128 tile, BK=32, 4 waves
// each computing 64x64 via 4x4 grid of 16x16x32 bf16 MFMAs.
// A,Bt row-major bf16.  global_load_lds width=16 staging (wave-uniform LDS base).
// EPI: 0 = qkv (bf16 out, piecewise bias b0/b1/b2)
//      1 = residual add (outF += acc + bias)
//      2 = gelu -> bf16 out
//      3 = plain fp32 out
template <int EPI>
__global__ __launch_bounds__(256) void gemm_bf16(const ushort* __restrict__ A,
                                                 const ushort* __restrict__ Bt,
                                                 const float* __restrict__ b0,
                                                 const float* __restrict__ b1,
                                                 const float* __restrict__ b2,
                                                 float* __restrict__ outF,
                                                 ushort* __restrict__ outB,
                                                 int N, int K) {
    __shared__ ushort Al[128 * 32];
    __shared__ ushort Bl[128 * 32];
    const int tid = threadIdx.x;
    const int wave = tid >> 6, lane = tid & 63;
    const int wm = wave >> 1, wn = wave & 1;
    const int l15 = lane & 15, q4 = lane >> 4;
    const int m0 = blockIdx.y * 128, n0 = blockIdx.x * 128;

    const ushort* Ag0 = A + (size_t)(m0 + wave * 16 + (lane >> 2)) * K + (lane & 3) * 8;
    const ushort* Ag1 = Ag0 + (size_t)64 * K;
    const ushort* Bg0 = Bt + (size_t)(n0 + wave * 16 + (lane >> 2)) * K + (lane & 3) * 8;
    const ushort* Bg1 = Bg0 + (size_t)64 * K;
    ushort* Al0 = &Al[(wave * 16) * 32];
    ushort* Al1 = &Al[(64 + wave * 16) * 32];
    ushort* Bl0 = &Bl[(wave * 16) * 32];
    ushort* Bl1 = &Bl[(64 + wave * 16) * 32];

    f32x4 acc[4][4];
#pragma unroll
    for (int i = 0; i < 4; i++)
#pragma unroll
        for (int j = 0; j < 4; j++) acc[i][j] = (f32x4){0.f, 0.f, 0.f, 0.f};

    for (int k0 = 0; k0 < K; k0 += 32) {
        __syncthreads();  // prior MFMA reads of LDS complete
        gload16(Ag0 + k0, Al0);
        gload16(Ag1 + k0, Al1);
        gload16(Bg0 + k0, Bl0);
        gload16(Bg1 + k0, Bl1);
        __syncthreads();  // compiler drains vmcnt before s_barrier
        bf16x8 af[4], bfr[4];
#pragma unroll
        for (int i = 0; i < 4; i++)
            af[i] = *(const bf16x8*)&Al[(wm * 64 + i * 16 + l15) * 32 + q4 * 8];
#pragma unroll
        for (int j = 0; j < 4; j++)
            bfr[j] = *(const bf16x8*)&Bl[(wn * 64 + j * 16 + l15) * 32 + q4 * 8];
#pragma unroll
        for (int i = 0; i < 4; i++)
#pragma unroll
            for (int j = 0; j < 4; j++)
                acc[i][j] = __builtin_amdgcn_mfma_f32_16x16x32_bf16(af[i], bfr[j], acc[i][j], 0, 0, 0);
    }

#pragma unroll
    for (int i = 0; i < 4; i++) {
        const int row = m0 + wm * 64 + i * 16 + q4 * 4;
#pragma unroll
        for (int j = 0; j < 4; j++) {
            const int col = n0 + wn * 64 + j * 16 + l15;
            float bias;
            if constexpr (EPI == 0)
                bias = (col < 768) ? b0[col] : (col < 1536 ? b1[col - 768] : b2[col - 1536]);
            else
                bias = b0[col];
#pragma unroll
            for (int r = 0; r < 4; r++) {
                const float v = acc[i][j][r] + bias;
                const size_t idx = (size_t)(row + r) * N + col;
                if constexpr (EPI == 0) {
                    outB[idx] = f2bf(v);
                } else if constexpr (EPI == 1) {
                    outF[idx] += v;
                } else if constexpr (EPI == 2) {
                    outB[idx] = f2bf(0.5f * v * (1.0f + erff(v * 0.70710678118654752f)));
                } else {
                    outF[idx] = v;
                }
            }
        }
    }
}

// ----------------------------------------------------- MFMA attention ----
// flash-style causal attention, bf16 MFMA.  qkv [T][2304] bf16 (q|k|v each
// [T][768] head-major h*64+d).  One block per (64-q-tile, head); wave w owns
// q rows w*16..w*16+15.  LDS rows padded to 72 bf16 (144B).
//
// R4 changes (latency-bound: MfmaUtil 2.3%, 7.7M LDS bank-conflict cycles,
// FETCH 23.4MB vs 9.4MB buffer):
//  (a) XCD-aware block remap: bid&7 pins a head's 32 q-blocks to one XCD so
//      K/V (512KB/head) stays L2-resident; qt descending for balance.
//  (b) VT/Ps XOR-swizzle (col ^ ((row-group)<<3)): the old scalar scatter
//      VT[(8ch+j)*72+row] had 288ch = 0 (mod 32) -> all 8 ch lanes on one
//      bank (16-way conflict).  Swizzle spreads writes across all 32 banks;
//      8-key groups stay contiguous so bf16x8 reads just XOR their base.
//  (c) T14 prefetch: next K/V tile loaded into regs during compute; the two
//      mid-iteration barriers are raw s_barrier + lgkmcnt(0)-only waits so
//      the in-flight global loads are NOT drained (a __syncthreads would
//      wait vmcnt(0)).  Top-of-loop __syncthreads keeps full-drain safety.
__global__ __launch_bounds__(256) void attn_mfma(const ushort* __restrict__ qkv,
                                                 ushort* __restrict__ o_bf) {
    __shared__ ushort Qs[64 * 72];
    __shared__ ushort Ks[64 * 72];
    __shared__ ushort Ps[64 * 72];
    __shared__ ushort VT[64 * 72];  // V transposed: [d][key ^ ((d>>3)<<3)]

    // (a) block remap: XCD = bid&7 (dispatch heuristic).  heads 0..7 -> own
    // XCD (32 blocks, qt 31..0); heads 8..11 -> split over 2 XCDs each.
    // second batch uses ascending qt so a CU hosting (r, r+32) pairs a big
    // tile with a small one.
    const int bid = blockIdx.x;
    const int x = bid & 7, r = bid >> 3;
    int hd, qt;
    if (r < 32) { hd = x;            qt = 31 - r; }
    else        { hd = 8 + (x & 3);  qt = (r - 32) * 2 + (x >> 2); }

    const int tid = threadIdx.x;
    const int wave = tid >> 6, lane = tid & 63;
    const int l15 = lane & 15, q4 = lane >> 4;
    const int rw = tid >> 3;      // 0..31: row within 32-row pass
    const int ch = tid & 7;       // 0..7: 16B chunk within 128B row

#pragma unroll
    for (int p = 0; p < 2; p++) {
        const int row = rw + p * 32;
        *(uint4*)&Qs[row * 72 + ch * 8] =
            *(const uint4*)&qkv[(size_t)(qt * 64 + row) * QKVN + hd * 64 + ch * 8];
    }

    // (c) prologue: tile kt=0 K/V into regs
    const ushort* kg = qkv + 768 + hd * 64 + ch * 8;
    const ushort* vg = qkv + 1536 + hd * 64 + ch * 8;
    uint4 kcur[2], vcur[2], knxt[2], vnxt[2];
#pragma unroll
    for (int p = 0; p < 2; p++) {
        kcur[p] = *(const uint4*)&kg[(size_t)(rw + p * 32) * QKVN];
        vcur[p] = *(const uint4*)&vg[(size_t)(rw + p * 32) * QKVN];
    }

    float m_i[4] = {-1e30f, -1e30f, -1e30f, -1e30f};
    float l_i[4] = {0.f, 0.f, 0.f, 0.f};
    f32x4 oacc[4];
#pragma unroll
    for (int n = 0; n < 4; n++) oacc[n] = (f32x4){0.f, 0.f, 0.f, 0.f};

    for (int kt = 0; kt <= qt; kt++) {
        __syncthreads();  // all waves done reading Ks/VT/Ps of prev iter
                          // (also drains the prefetch vmcnt; regs used next)
        // write K rows + swizzled V^T from regs
#pragma unroll
        for (int p = 0; p < 2; p++) {
            const int row = rw + p * 32;
            *(uint4*)&Ks[row * 72 + ch * 8] = kcur[p];
            const uint4 w = vcur[p];
            const int swz = row ^ (ch << 3);          // key ^ ((d>>3)<<3), d>>3==ch
            ushort* vt = &VT[(ch * 8) * 72 + swz];
            vt[0 * 72] = (ushort)(w.x & 0xffff);
            vt[1 * 72] = (ushort)(w.x >> 16);
            vt[2 * 72] = (ushort)(w.y & 0xffff);
            vt[3 * 72] = (ushort)(w.y >> 16);
            vt[4 * 72] = (ushort)(w.z & 0xffff);
            vt[5 * 72] = (ushort)(w.z >> 16);
            vt[6 * 72] = (ushort)(w.w & 0xffff);
            vt[7 * 72] = (ushort)(w.w >> 16);
        }
        // (c) issue next-tile loads; they stay in flight across the raw barriers
        if (kt < qt) {
#pragma unroll
            for (int p = 0; p < 2; p++) {
                knxt[p] = *(const uint4*)&kg[(size_t)((kt + 1) * 64 + rw + p * 32) * QKVN];
                vnxt[p] = *(const uint4*)&vg[(size_t)((kt + 1) * 64 + rw + p * 32) * QKVN];
            }
        }
        asm volatile("s_waitcnt lgkmcnt(0)" ::: "memory");  // LDS writes visible
        __builtin_amdgcn_s_barrier();                       // (no vmcnt drain)

        // S = Q K^T for this wave's 16 q-rows (4 key-tiles of 16)
        f32x4 s[4];
#pragma unroll
        for (int n = 0; n < 4; n++) {
            f32x4 a = (f32x4){0.f, 0.f, 0.f, 0.f};
#pragma unroll
            for (int kb = 0; kb < 2; kb++) {
                const bf16x8 qa = *(const bf16x8*)&Qs[(wave * 16 + l15) * 72 + kb * 32 + q4 * 8];
                const bf16x8 kf = *(const bf16x8*)&Ks[(n * 16 + l15) * 72 + kb * 32 + q4 * 8];
                a = __builtin_amdgcn_mfma_f32_16x16x32_bf16(qa, kf, a, 0, 0, 0);
            }
            s[n] = a;
        }

        const bool diag = (kt == qt);
        float alpha[4];
#pragma unroll
        for (int rr = 0; rr < 4; rr++) {
            const int qrow = wave * 16 + q4 * 4 + rr;  // local within 64-q tile
            float sv[4];
            float mx = -1e30f;
#pragma unroll
            for (int n = 0; n < 4; n++) {
                float xv = s[n][rr] * ATT_SCALE;
                if (diag && (n * 16 + l15) > qrow) xv = -1e30f;
                sv[n] = xv;
                mx = fmaxf(mx, xv);
            }
#pragma unroll
            for (int msk = 1; msk < 16; msk <<= 1) mx = fmaxf(mx, __shfl_xor(mx, msk, 64));
            const float nm = fmaxf(m_i[rr], mx);
            const float al = __expf(m_i[rr] - nm);
            float rs = 0.f;
            float pe[4];
#pragma unroll
            for (int n = 0; n < 4; n++) {
                pe[n] = __expf(sv[n] - nm);
                rs += pe[n];
            }
#pragma unroll
            for (int msk = 1; msk < 16; msk <<= 1) rs += __shfl_xor(rs, msk, 64);
            l_i[rr] = l_i[rr] * al + rs;
            m_i[rr] = nm;
            alpha[rr] = al;
            // P in A-operand layout, col-swizzled: Ps[qrow][col ^ ((qrow&7)<<3)]
            const int ps = (qrow & 7) << 3;
#pragma unroll
            for (int n = 0; n < 4; n++)
                Ps[qrow * 72 + ((n * 16 + l15) ^ ps)] = f2bf(pe[n]);
        }
#pragma unroll
        for (int n = 0; n < 4; n++) {
            oacc[n][0] *= alpha[0];
            oacc[n][1] *= alpha[1];
            oacc[n][2] *= alpha[2];
            oacc[n][3] *= alpha[3];
        }
        asm volatile("s_waitcnt lgkmcnt(0)" ::: "memory");  // Ps writes visible
        __builtin_amdgcn_s_barrier();                       // (no vmcnt drain)

        // O += P V   (4 d-tiles of 16)
        const int prow = wave * 16 + l15;
        const int psw = (prow & 7) << 3;
#pragma unroll
        for (int n = 0; n < 4; n++) {
            const int drow = n * 16 + l15;
            const int vsw = ((drow >> 3) & 7) << 3;
#pragma unroll
            for (int kb = 0; kb < 2; kb++) {
                const int c0 = kb * 32 + q4 * 8;
                const bf16x8 pa = *(const bf16x8*)&Ps[prow * 72 + (c0 ^ psw)];
                const bf16x8 vb = *(const bf16x8*)&VT[drow * 72 + (c0 ^ vsw)];
                oacc[n] = __builtin_amdgcn_mfma_f32_16x16x32_bf16(pa, vb, oacc[n], 0, 0, 0);
            }
        }

        if (kt < qt) {
            kcur[0] = knxt[0]; kcur[1] = knxt[1];
            vcur[0] = vnxt[0]; vcur[1] = vnxt[1];
        }
    }

#pragma unroll
    for (int n = 0; n < 4; n++)
#pragma unroll
        for (int rr = 0; rr < 4; rr++) {
            const float v = oacc[n][rr] / l_i[rr];
            o_bf[(size_t)(qt * 64 + wave * 16 + q4 * 4 + rr) * EE + hd * 64 + n * 16 + l15] = f2bf(v);
        }
}

// ---------------------------------------------------------------- head ----
__global__ __launch_bounds__(256) void head_kernel(const float* __restrict__ x,
                                                   const float* __restrict__ hw,
                                                   const float* __restrict__ hb,
                                                   float* __restrict__ out) {
    __shared__ float red[8];
    const int t = blockIdx.x, tid = threadIdx.x;
    const float* row = x + (size_t)t * EE;
    float s = row[tid] * hw[tid] + row[tid + 256] * hw[tid + 256] + row[tid + 512] * hw[tid + 512];
#pragma unroll
    for (int m = 1; m < 64; m <<= 1) s += __shfl_xor(s, m, 64);
    if ((tid & 63) == 0) red[tid >> 6] = s;
    __syncthreads();
    if (tid == 0) out[t] = red[0] + red[1] + red[2] + red[3] + hb[0];
}

// -------------------------------------------------------------- launch ----
extern "C" void kernel_launch(void* const* d_in, const int* in_sizes, int n_in,
                              void* d_out, int out_size, void* d_ws, size_t ws_size,
                              hipStream_t stream) {
    const float* idx   = (const float*)d_in[0];
    const float* wq    = (const float*)d_in[2];
    const float* bq    = (const float*)d_in[3];
    const float* wk    = (const float*)d_in[4];
    const float* bk    = (const float*)d_in[5];
    const float* wv    = (const float*)d_in[6];
    const float* bv    = (const float*)d_in[7];
    const float* wproj = (const float*)d_in[8];
    const float* bproj = (const float*)d_in[9];
    const float* ln1g  = (const float*)d_in[10];
    const float* ln1b  = (const float*)d_in[11];
    const float* ln2g  = (const float*)d_in[12];
    const float* ln2b  = (const float*)d_in[13];
    const float* w1    = (const float*)d_in[14];
    const float* b1    = (const float*)d_in[15];
    const float* w2    = (const float*)d_in[16];
    const float* b2    = (const float*)d_in[17];
    const float* lnfg  = (const float*)d_in[18];
    const float* lnfb  = (const float*)d_in[19];
    const float* fw1   = (const float*)d_in[20];
    const float* fb1   = (const float*)d_in[21];
    const float* fw2   = (const float*)d_in[22];
    const float* fb2   = (const float*)d_in[23];
    const float* hw    = (const float*)d_in[24];
    const float* hb    = (const float*)d_in[25];
    float* out = (float*)d_out;

    // ---- workspace carve (~47 MB) ----
    char* p = (char*)d_ws;
    auto alloc = [&](size_t bytes) { void* r = (void*)p; p += (bytes + 255) & ~(size_t)255; return r; };
    float*  x     = (float*)alloc((size_t)TT * EE * 4);
    ushort* h_bf  = (ushort*)alloc((size_t)TT * EE * 2);
    ushort* qkvb  = (ushort*)alloc((size_t)TT * QKVN * 2);
    ushort* o_bf  = (ushort*)alloc((size_t)TT * EE * 2);
    ushort* ffb   = (ushort*)alloc((size_t)TT * FFD * 2);
    ushort* Wqkv  = (ushort*)alloc((size_t)QKVN * EE * 2);
    ushort* Wproj = (ushort*)alloc((size_t)EE * EE * 2);
    ushort* W1t   = (ushort*)alloc((size_t)FFD * EE * 2);
    ushort* W2t   = (ushort*)alloc((size_t)EE * FFD * 2);

    // only batch 3 contributes to the output (logits[-1]; no cross-batch mixing)
    copy4_kernel<<<dim3((TT * EE / 4 + 255) / 256), dim3(256), 0, stream>>>(
        (float4*)x, (const float4*)(idx + (size_t)3 * TT * EE), TT * EE / 4);

    for (int l = 0; l < NLAYER; l++) {
        const size_t lw = (size_t)l;
        pack_qkv_kernel<<<dim3(12, 1, 36), dim3(256), 0, stream>>>(
            wq + lw * HNN * EE * HSS, wk + lw * HNN * EE * HSS, wv + lw * HNN * EE * HSS, Wqkv);
        pack_t_kernel<<<dim3(12, 12), dim3(256), 0, stream>>>(wproj + lw * EE * EE, EE, Wproj, EE);
        pack_t_kernel<<<dim3(12, 48), dim3(256), 0, stream>>>(w1 + lw * EE * FFD, FFD, W1t, EE);
        pack_t_kernel<<<dim3(48, 12), dim3(256), 0, stream>>>(w2 + lw * FFD * EE, EE, W2t, FFD);

        ln_kernel<<<dim3(TT), dim3(256), 0, stream>>>(x, ln1g + lw * EE, ln1b + lw * EE, h_bf);
        gemm_bf16<0><<<dim3(QKVN / 128, TT / 128), dim3(256), 0, stream>>>(
            h_bf, Wqkv, bq + lw * EE, bk + lw * EE, bv + lw * EE, nullptr, qkvb, QKVN, EE);
        attn_mfma<<<dim3(384), dim3(256), 0, stream>>>(qkvb, o_bf);
        gemm_bf16<1><<<dim3(EE / 128, TT / 128), dim3(256), 0, stream>>>(
            o_bf, Wproj, bproj + lw * EE, nullptr, nullptr, x, nullptr, EE, EE);
        ln_kernel<<<dim3(TT), dim3(256), 0, stream>>>(x, ln2g + lw * EE, ln2b + lw * EE, h_bf);
        gemm_bf16<2><<<dim3(FFD / 128, TT / 128), dim3(256), 0, stream>>>(
            h_bf, W1t, b1 + lw * FFD, nullptr, nullptr, nullptr, ffb, FFD, EE);
        gemm_bf16<1><<<dim3(EE / 128, TT / 128), dim3(256), 0, stream>>>(
            ffb, W2t, b2 + lw * EE, nullptr, nullptr, x, nullptr, EE, FFD);
    }

    ln_kernel<<<dim3(TT), dim3(256), 0, stream>>>(x, lnfg, lnfb, h_bf);
    pack_t_kernel<<<dim3(12, 48), dim3(256), 0, stream>>>(fw1, FFD, W1t, EE);
    pack_t_kernel<<<dim3(48, 12), dim3(256), 0, stream>>>(fw2, EE, W2t, FFD);
    gemm_bf16<2><<<dim3(FFD / 128, TT / 128), dim3(256), 0, stream>>>(
        h_bf, W1t, fb1, nullptr, nullptr, nullptr, ffb, FFD, EE);
    gemm_bf16<3><<<dim3(EE / 128, TT / 128), dim3(256), 0, stream>>>(
        ffb, W2t, fb2, nullptr, nullptr, x, nullptr, EE, FFD);
    head_kernel<<<dim3(TT), dim3(256), 0, stream>>>(x, hw, hb, out);
}

// Round 2
// 1962.453 us; speedup vs baseline: 1.0588x; 1.0042x over previous
//
#include <hip/hip_runtime.h>
#include <math.h>

#define TT 2048
#define EE 768
#define HNN 12
#define HSS 64
#define NLAYER 6
#define FFD 3072
#define QKVN 2304

constexpr float LN_EPS = 1e-5f;
constexpr float ATT_SCALE = 0.03608439182435161f; // 1/sqrt(768) (reference divides by sqrt(n_embed))

typedef __attribute__((ext_vector_type(8))) short bf16x8;
typedef __attribute__((ext_vector_type(4))) float f32x4;

__device__ __forceinline__ ushort f2bf(float f) {
    union { float f; uint u; } c; c.f = f;
    const uint u = c.u;
    return (ushort)((u + 0x7fffu + ((u >> 16) & 1u)) >> 16);
}

__device__ __forceinline__ void gload16(const void* g, void* l) {
    __builtin_amdgcn_global_load_lds((const __attribute__((address_space(1))) void*)g,
                                     (__attribute__((address_space(3))) void*)l, 16, 0, 0);
}

// ---------------------------------------------------------------- copy ----
__global__ __launch_bounds__(256) void copy4_kernel(float4* __restrict__ dst,
                                                    const float4* __restrict__ src, int n4) {
    int i = blockIdx.x * 256 + threadIdx.x;
    if (i < n4) dst[i] = src[i];
}

// ----------------------------------------------------------- layernorm ----
// one block (256 thr) per token; E=768 = 3*256.  fp32 in -> bf16 out.
__global__ __launch_bounds__(256) void ln_kernel(const float* __restrict__ in,
                                                 const float* __restrict__ g,
                                                 const float* __restrict__ b,
                                                 ushort* __restrict__ out) {
    __shared__ float red[8];
    const int t = blockIdx.x;
    const int tid = threadIdx.x;
    const float* row = in + (size_t)t * EE;
    float v0 = row[tid], v1 = row[tid + 256], v2 = row[tid + 512];
    float s = v0 + v1 + v2;
#pragma unroll
    for (int m = 1; m < 64; m <<= 1) s += __shfl_xor(s, m, 64);
    if ((tid & 63) == 0) red[tid >> 6] = s;
    __syncthreads();
    const float mean = (red[0] + red[1] + red[2] + red[3]) * (1.0f / EE);
    const float d0 = v0 - mean, d1 = v1 - mean, d2 = v2 - mean;
    float qq = d0 * d0 + d1 * d1 + d2 * d2;
#pragma unroll
    for (int m = 1; m < 64; m <<= 1) qq += __shfl_xor(qq, m, 64);
    __syncthreads();
    if ((tid & 63) == 0) red[tid >> 6] = qq;
    __syncthreads();
    const float var = (red[0] + red[1] + red[2] + red[3]) * (1.0f / EE);
    const float rstd = rsqrtf(var + LN_EPS);
    ushort* orow = out + (size_t)t * EE;
    orow[tid]       = f2bf(d0 * rstd * g[tid]       + b[tid]);
    orow[tid + 256] = f2bf(d1 * rstd * g[tid + 256] + b[tid + 256]);
    orow[tid + 512] = f2bf(d2 * rstd * g[tid + 512] + b[tid + 512]);
}

// --------------------------------------------------- weight pack (fp32->bf16^T)
// dst[n][k] (bf16, row stride dld) = src[k][n] (fp32, row stride sld), 64x64 tile
__device__ __forceinline__ void transpose64(const float* __restrict__ src, int sld,
                                            ushort* __restrict__ dst, int dld,
                                            int k0, int n0, int tid) {
    __shared__ float t[64][68];
#pragma unroll
    for (int p = 0; p < 4; p++) {
        const int kr = p * 16 + (tid >> 4);
        *(float4*)&t[kr][(tid & 15) * 4] =
            *(const float4*)&src[(size_t)(k0 + kr) * sld + n0 + (tid & 15) * 4];
    }
    __syncthreads();
#pragma unroll
    for (int q = 0; q < 2; q++) {
        const int nl = q * 32 + (tid >> 3);
        const int kc = (tid & 7) * 8;
        ushort v[8];
#pragma unroll
        for (int j = 0; j < 8; j++) v[j] = f2bf(t[kc + j][nl]);
        uint4 o;
        o.x = (uint)v[0] | ((uint)v[1] << 16);
        o.y = (uint)v[2] | ((uint)v[3] << 16);
        o.z = (uint)v[4] | ((uint)v[5] << 16);
        o.w = (uint)v[6] | ((uint)v[7] << 16);
        *(uint4*)&dst[(size_t)(n0 + nl) * dld + k0 + kc] = o;
    }
}

__global__ __launch_bounds__(256) void pack_t_kernel(const float* __restrict__ src, int sld,
                                                     ushort* __restrict__ dst, int dld) {
    transpose64(src, sld, dst, dld, blockIdx.x * 64, blockIdx.y * 64, threadIdx.x);
}

// qkv weights [HN][E][HS] (3 tensors) -> Wqkv_t[2304][768] bf16 (row n = which*768+h*64+s)
__global__ __launch_bounds__(256) void pack_qkv_kernel(const float* __restrict__ wq,
                                                       const float* __restrict__ wk,
                                                       const float* __restrict__ wv,
                                                       ushort* __restrict__ dst) {
    const int z = blockIdx.z;
    const int which = z / HNN, hd = z % HNN;
    const float* src = (which == 0 ? wq : which == 1 ? wk : wv) + (size_t)hd * EE * HSS;
    ushort* d = dst + (size_t)(which * EE + hd * HSS) * EE;
    transpose64(src, HSS, d, EE, blockIdx.x * 64, 0, threadIdx.x);
}

// ---------------------------------------------------------- bf16 GEMM ----
// C[M,N] = epi(A[M,K] @ Bt[N,K]^T + bias).  128x128 tile, BK=32, 4 waves
// each computing 64x64 via 4x4 grid of 16x16x32 bf16 MFMAs.
// A,Bt row-major bf16.  global_load_lds width=16 staging (wave-uniform LDS base).
// EPI: 0 = qkv (bf16 out, piecewise bias b0/b1/b2)
//      1 = residual add (outF += acc + bias)
//      2 = gelu -> bf16 out
//      3 = plain fp32 out
template <int EPI>
__global__ __launch_bounds__(256) void gemm_bf16(const ushort* __restrict__ A,
                                                 const ushort* __restrict__ Bt,
                                                 const float* __restrict__ b0,
                                                 const float* __restrict__ b1,
                                                 const float* __restrict__ b2,
                                                 float* __restrict__ outF,
                                                 ushort* __restrict__ outB,
                                                 int N, int K) {
    __shared__ ushort Al[128 * 32];
    __shared__ ushort Bl[128 * 32];
    const int tid = threadIdx.x;
    const int wave = tid >> 6, lane = tid & 63;
    const int wm = wave >> 1, wn = wave & 1;
    const int l15 = lane & 15, q4 = lane >> 4;
    const int m0 = blockIdx.y * 128, n0 = blockIdx.x * 128;

    const ushort* Ag0 = A + (size_t)(m0 + wave * 16 + (lane >> 2)) * K + (lane & 3) * 8;
    const ushort* Ag1 = Ag0 + (size_t)64 * K;
    const ushort* Bg0 = Bt + (size_t)(n0 + wave * 16 + (lane >> 2)) * K + (lane & 3) * 8;
    const ushort* Bg1 = Bg0 + (size_t)64 * K;
    ushort* Al0 = &Al[(wave * 16) * 32];
    ushort* Al1 = &Al[(64 + wave * 16) * 32];
    ushort* Bl0 = &Bl[(wave * 16) * 32];
    ushort* Bl1 = &Bl[(64 + wave * 16) * 32];

    f32x4 acc[4][4];
#pragma unroll
    for (int i = 0; i < 4; i++)
#pragma unroll
        for (int j = 0; j < 4; j++) acc[i][j] = (f32x4){0.f, 0.f, 0.f, 0.f};

    for (int k0 = 0; k0 < K; k0 += 32) {
        __syncthreads();  // prior MFMA reads of LDS complete
        gload16(Ag0 + k0, Al0);
        gload16(Ag1 + k0, Al1);
        gload16(Bg0 + k0, Bl0);
        gload16(Bg1 + k0, Bl1);
        __syncthreads();  // compiler drains vmcnt before s_barrier
        bf16x8 af[4], bfr[4];
#pragma unroll
        for (int i = 0; i < 4; i++)
            af[i] = *(const bf16x8*)&Al[(wm * 64 + i * 16 + l15) * 32 + q4 * 8];
#pragma unroll
        for (int j = 0; j < 4; j++)
            bfr[j] = *(const bf16x8*)&Bl[(wn * 64 + j * 16 + l15) * 32 + q4 * 8];
#pragma unroll
        for (int i = 0; i < 4; i++)
#pragma unroll
            for (int j = 0; j < 4; j++)
                acc[i][j] = __builtin_amdgcn_mfma_f32_16x16x32_bf16(af[i], bfr[j], acc[i][j], 0, 0, 0);
    }

#pragma unroll
    for (int i = 0; i < 4; i++) {
        const int row = m0 + wm * 64 + i * 16 + q4 * 4;
#pragma unroll
        for (int j = 0; j < 4; j++) {
            const int col = n0 + wn * 64 + j * 16 + l15;
            float bias;
            if constexpr (EPI == 0)
                bias = (col < 768) ? b0[col] : (col < 1536 ? b1[col - 768] : b2[col - 1536]);
            else
                bias = b0[col];
#pragma unroll
            for (int r = 0; r < 4; r++) {
                const float v = acc[i][j][r] + bias;
                const size_t idx = (size_t)(row + r) * N + col;
                if constexpr (EPI == 0) {
                    outB[idx] = f2bf(v);
                } else if constexpr (EPI == 1) {
                    outF[idx] += v;
                } else if constexpr (EPI == 2) {
                    outB[idx] = f2bf(0.5f * v * (1.0f + erff(v * 0.70710678118654752f)));
                } else {
                    outF[idx] = v;
                }
            }
        }
    }
}

// ----------------------------------------------------- MFMA attention ----
// flash-style causal attention, bf16 MFMA.  qkv [T][2304] bf16.
// One block per (64-q-tile, head); wave w owns q rows w*16..w*16+15.
//
// R5 restructure (latency-bound: 8-deep shfl chain + 3 sync points/iter):
//  - SWAPPED QK^T: mfma(K_frag, Q_frag) -> lane holds 16 keys of ONE q-row
//    (q-row = wave*16+l15).  Row max/sum = in-register 16-tree + 2 shfl_xor
//    (masks 16,32) instead of 4-step shfl per reduction; m/l are per-lane
//    scalars.  alpha/l redistributed to O-layout (rows q4*4+r) via 4 shfls.
//  - P round-trip through per-wave LDS (4x ds_write_b64 packed + 2x
//    ds_read_b128, XOR-swizzled dword cols) -- intra-wave only, so NO
//    barrier between softmax and PV.
//  - Double-buffered Ks/VT + register prefetch of kt+1 during compute of kt:
//    exactly ONE __syncthreads per iteration (was 3 sync points).
//  - Q fragments live in registers (loaded once).
//  - XCD remap kept from R4 (FETCH 23.4->6.6MB).
__global__ __launch_bounds__(256) void attn_mfma(const ushort* __restrict__ qkv,
                                                 ushort* __restrict__ o_bf) {
    __shared__ __align__(16) ushort Ks[2][64 * 72];
    __shared__ __align__(16) ushort VT[2][64 * 72];  // V^T: [d][key ^ ((d>>3)<<3)]
    __shared__ __align__(16) uint   Ps[4][16 * 36];  // per-wave P rows (dwords)

    const int bid = blockIdx.x;
    const int x = bid & 7, r = bid >> 3;
    int hd, qt;
    if (r < 32) { hd = x;            qt = 31 - r; }
    else        { hd = 8 + (x & 3);  qt = (r - 32) * 2 + (x >> 2); }

    const int tid = threadIdx.x;
    const int wave = tid >> 6, lane = tid & 63;
    const int l15 = lane & 15, q4 = lane >> 4;
    const int rw = tid >> 3;      // 0..31: row within 32-row pass
    const int ch = tid & 7;       // 0..7: 16B chunk within 128B row

    // Q fragments (B-operand of swapped QK^T) -> registers, loaded once
    bf16x8 qa0, qa1;
    {
        const ushort* qrow = qkv + (size_t)(qt * 64 + wave * 16 + l15) * QKVN + hd * 64;
        qa0 = *(const bf16x8*)&qrow[q4 * 8];
        qa1 = *(const bf16x8*)&qrow[32 + q4 * 8];
    }

    const ushort* kg = qkv + 768 + hd * 64 + ch * 8;
    const ushort* vg = qkv + 1536 + hd * 64 + ch * 8;

    // stage kt=0 into buffer 0
#pragma unroll
    for (int p = 0; p < 2; p++) {
        const int row = rw + p * 32;
        const uint4 kv = *(const uint4*)&kg[(size_t)row * QKVN];
        *(uint4*)&Ks[0][row * 72 + ch * 8] = kv;
        const uint4 w = *(const uint4*)&vg[(size_t)row * QKVN];
        const int swz = row ^ (ch << 3);
        ushort* vt = &VT[0][(ch * 8) * 72 + swz];
        vt[0 * 72] = (ushort)(w.x & 0xffff);
        vt[1 * 72] = (ushort)(w.x >> 16);
        vt[2 * 72] = (ushort)(w.y & 0xffff);
        vt[3 * 72] = (ushort)(w.y >> 16);
        vt[4 * 72] = (ushort)(w.z & 0xffff);
        vt[5 * 72] = (ushort)(w.z >> 16);
        vt[6 * 72] = (ushort)(w.w & 0xffff);
        vt[7 * 72] = (ushort)(w.w >> 16);
    }
    __syncthreads();

    float m_i = -1e30f;   // running max for q-row (wave*16 + l15)
    float l_i = 0.f;      // running sum for q-row (wave*16 + l15)
    f32x4 oacc[4];
#pragma unroll
    for (int n = 0; n < 4; n++) oacc[n] = (f32x4){0.f, 0.f, 0.f, 0.f};

    for (int kt = 0; kt <= qt; kt++) {
        const int buf = kt & 1;
        const bool more = (kt < qt);
        uint4 knxt[2], vnxt[2];
        if (more) {
#pragma unroll
            for (int p = 0; p < 2; p++) {
                knxt[p] = *(const uint4*)&kg[(size_t)((kt + 1) * 64 + rw + p * 32) * QKVN];
                vnxt[p] = *(const uint4*)&vg[(size_t)((kt + 1) * 64 + rw + p * 32) * QKVN];
            }
        }

        // S^T = K Q^T : lane -> q-row (wave*16+l15), keys n*16+q4*4+r
        const ushort* Kb = &Ks[buf][0];
        f32x4 s[4];
#pragma unroll
        for (int n = 0; n < 4; n++) {
            const bf16x8 kf0 = *(const bf16x8*)&Kb[(n * 16 + l15) * 72 + q4 * 8];
            const bf16x8 kf1 = *(const bf16x8*)&Kb[(n * 16 + l15) * 72 + 32 + q4 * 8];
            f32x4 a = (f32x4){0.f, 0.f, 0.f, 0.f};
            a = __builtin_amdgcn_mfma_f32_16x16x32_bf16(kf0, qa0, a, 0, 0, 0);
            a = __builtin_amdgcn_mfma_f32_16x16x32_bf16(kf1, qa1, a, 0, 0, 0);
            s[n] = a;
        }

        const bool diag = (kt == qt);
        const int qrl = wave * 16 + l15;
        float pe[16];
        float mx = -1e30f;
#pragma unroll
        for (int n = 0; n < 4; n++)
#pragma unroll
            for (int rr = 0; rr < 4; rr++) {
                float xv = s[n][rr] * ATT_SCALE;
                if (diag && (n * 16 + q4 * 4 + rr) > qrl) xv = -1e30f;
                pe[n * 4 + rr] = xv;
                mx = fmaxf(mx, xv);
            }
        mx = fmaxf(mx, __shfl_xor(mx, 16, 64));
        mx = fmaxf(mx, __shfl_xor(mx, 32, 64));
        const float nm = fmaxf(m_i, mx);
        const float al = __expf(m_i - nm);
        float rs = 0.f;
#pragma unroll
        for (int i = 0; i < 16; i++) {
            pe[i] = __expf(pe[i] - nm);
            rs += pe[i];
        }
        rs += __shfl_xor(rs, 16, 64);
        rs += __shfl_xor(rs, 32, 64);
        l_i = l_i * al + rs;
        m_i = nm;

        // alpha for O-rows q4*4+rr (O acc layout) from per-q-row lanes
        float alr[4];
#pragma unroll
        for (int rr = 0; rr < 4; rr++) alr[rr] = __shfl(al, q4 * 4 + rr, 64);
#pragma unroll
        for (int n = 0; n < 4; n++) {
            oacc[n][0] *= alr[0];
            oacc[n][1] *= alr[1];
            oacc[n][2] *= alr[2];
            oacc[n][3] *= alr[3];
        }

        // P -> per-wave LDS (packed b64 writes, swizzled) -> A-fragments.
        // Intra-wave round trip: no barrier (compiler lgkm ordering).
        uint* psrow = &Ps[wave][l15 * 36];
        const int psx = (l15 & 7) << 2;
#pragma unroll
        for (int n = 0; n < 4; n++) {
            uint2 d;
            d.x = (uint)f2bf(pe[n * 4 + 0]) | ((uint)f2bf(pe[n * 4 + 1]) << 16);
            d.y = (uint)f2bf(pe[n * 4 + 2]) | ((uint)f2bf(pe[n * 4 + 3]) << 16);
            *(uint2*)&psrow[(n * 8 + q4 * 2) ^ psx] = d;
        }
        const bf16x8 pa0 = *(const bf16x8*)&psrow[(q4 * 4) ^ psx];
        const bf16x8 pa1 = *(const bf16x8*)&psrow[(16 + q4 * 4) ^ psx];

        // O += P V   (4 d-tiles of 16)
        const ushort* Vb = &VT[buf][0];
#pragma unroll
        for (int n = 0; n < 4; n++) {
            const int drow = n * 16 + l15;
            const int vsw = ((drow >> 3) & 7) << 3;
            const bf16x8 vb0 = *(const bf16x8*)&Vb[drow * 72 + ((q4 * 8) ^ vsw)];
            const bf16x8 vb1 = *(const bf16x8*)&Vb[drow * 72 + ((32 + q4 * 8) ^ vsw)];
            oacc[n] = __builtin_amdgcn_mfma_f32_16x16x32_bf16(pa0, vb0, oacc[n], 0, 0, 0);
            oacc[n] = __builtin_amdgcn_mfma_f32_16x16x32_bf16(pa1, vb1, oacc[n], 0, 0, 0);
        }

        // stage kt+1 into the other buffer (loads were in flight all iter)
        if (more) {
#pragma unroll
            for (int p = 0; p < 2; p++) {
                const int row = rw + p * 32;
                *(uint4*)&Ks[buf ^ 1][row * 72 + ch * 8] = knxt[p];
                const uint4 w = vnxt[p];
                const int swz = row ^ (ch << 3);
                ushort* vt = &VT[buf ^ 1][(ch * 8) * 72 + swz];
                vt[0 * 72] = (ushort)(w.x & 0xffff);
                vt[1 * 72] = (ushort)(w.x >> 16);
                vt[2 * 72] = (ushort)(w.y & 0xffff);
                vt[3 * 72] = (ushort)(w.y >> 16);
                vt[4 * 72] = (ushort)(w.z & 0xffff);
                vt[5 * 72] = (ushort)(w.z >> 16);
                vt[6 * 72] = (ushort)(w.w & 0xffff);
                vt[7 * 72] = (ushort)(w.w >> 16);
            }
        }
        __syncthreads();
    }

    float lrec[4];
#pragma unroll
    for (int rr = 0; rr < 4; rr++) lrec[rr] = 1.0f / __shfl(l_i, q4 * 4 + rr, 64);
#pragma unroll
    for (int n = 0; n < 4; n++)
#pragma unroll
        for (int rr = 0; rr < 4; rr++)
            o_bf[(size_t)(qt * 64 + wave * 16 + q4 * 4 + rr) * EE + hd * 64 + n * 16 + l15] =
                f2bf(oacc[n][rr] * lrec[rr]);
}

// ---------------------------------------------------------------- head ----
__global__ __launch_bounds__(256) void head_kernel(const float* __restrict__ x,
                                                   const float* __restrict__ hw,
                                                   const float* __restrict__ hb,
                                                   float* __restrict__ out) {
    __shared__ float red[8];
    const int t = blockIdx.x, tid = threadIdx.x;
    const float* row = x + (size_t)t * EE;
    float s = row[tid] * hw[tid] + row[tid + 256] * hw[tid + 256] + row[tid + 512] * hw[tid + 512];
#pragma unroll
    for (int m = 1; m < 64; m <<= 1) s += __shfl_xor(s, m, 64);
    if ((tid & 63) == 0) red[tid >> 6] = s;
    __syncthreads();
    if (tid == 0) out[t] = red[0] + red[1] + red[2] + red[3] + hb[0];
}

// -------------------------------------------------------------- launch ----
extern "C" void kernel_launch(void* const* d_in, const int* in_sizes, int n_in,
                              void* d_out, int out_size, void* d_ws, size_t ws_size,
                              hipStream_t stream) {
    const float* idx   = (const float*)d_in[0];
    const float* wq    = (const float*)d_in[2];
    const float* bq    = (const float*)d_in[3];
    const float* wk    = (const float*)d_in[4];
    const float* bk    = (const float*)d_in[5];
    const float* wv    = (const float*)d_in[6];
    const float* bv    = (const float*)d_in[7];
    const float* wproj = (const float*)d_in[8];
    const float* bproj = (const float*)d_in[9];
    const float* ln1g  = (const float*)d_in[10];
    const float* ln1b  = (const float*)d_in[11];
    const float* ln2g  = (const float*)d_in[12];
    const float* ln2b  = (const float*)d_in[13];
    const float* w1    = (const float*)d_in[14];
    const float* b1    = (const float*)d_in[15];
    const float* w2    = (const float*)d_in[16];
    const float* b2    = (const float*)d_in[17];
    const float* lnfg  = (const float*)d_in[18];
    const float* lnfb  = (const float*)d_in[19];
    const float* fw1   = (const float*)d_in[20];
    const float* fb1   = (const float*)d_in[21];
    const float* fw2   = (const float*)d_in[22];
    const float* fb2   = (const float*)d_in[23];
    const float* hw    = (const float*)d_in[24];
    const float* hb    = (const float*)d_in[25];
    float* out = (float*)d_out;

    // ---- workspace carve (~47 MB) ----
    char* p = (char*)d_ws;
    auto alloc = [&](size_t bytes) { void* r = (void*)p; p += (bytes + 255) & ~(size_t)255; return r; };
    float*  x     = (float*)alloc((size_t)TT * EE * 4);
    ushort* h_bf  = (ushort*)alloc((size_t)TT * EE * 2);
    ushort* qkvb  = (ushort*)alloc((size_t)TT * QKVN * 2);
    ushort* o_bf  = (ushort*)alloc((size_t)TT * EE * 2);
    ushort* ffb   = (ushort*)alloc((size_t)TT * FFD * 2);
    ushort* Wqkv  = (ushort*)alloc((size_t)QKVN * EE * 2);
    ushort* Wproj = (ushort*)alloc((size_t)EE * EE * 2);
    ushort* W1t   = (ushort*)alloc((size_t)FFD * EE * 2);
    ushort* W2t   = (ushort*)alloc((size_t)EE * FFD * 2);

    // only batch 3 contributes to the output (logits[-1]; no cross-batch mixing)
    copy4_kernel<<<dim3((TT * EE / 4 + 255) / 256), dim3(256), 0, stream>>>(
        (float4*)x, (const float4*)(idx + (size_t)3 * TT * EE), TT * EE / 4);

    for (int l = 0; l < NLAYER; l++) {
        const size_t lw = (size_t)l;
        pack_qkv_kernel<<<dim3(12, 1, 36), dim3(256), 0, stream>>>(
            wq + lw * HNN * EE * HSS, wk + lw * HNN * EE * HSS, wv + lw * HNN * EE * HSS, Wqkv);
        pack_t_kernel<<<dim3(12, 12), dim3(256), 0, stream>>>(wproj + lw * EE * EE, EE, Wproj, EE);
        pack_t_kernel<<<dim3(12, 48), dim3(256), 0, stream>>>(w1 + lw * EE * FFD, FFD, W1t, EE);
        pack_t_kernel<<<dim3(48, 12), dim3(256), 0, stream>>>(w2 + lw * FFD * EE, EE, W2t, FFD);

        ln_kernel<<<dim3(TT), dim3(256), 0, stream>>>(x, ln1g + lw * EE, ln1b + lw * EE, h_bf);
        gemm_bf16<0><<<dim3(QKVN / 128, TT / 128), dim3(256), 0, stream>>>(
            h_bf, Wqkv, bq + lw * EE, bk + lw * EE, bv + lw * EE, nullptr, qkvb, QKVN, EE);
        attn_mfma<<<dim3(384), dim3(256), 0, stream>>>(qkvb, o_bf);
        gemm_bf16<1><<<dim3(EE / 128, TT / 128), dim3(256), 0, stream>>>(
            o_bf, Wproj, bproj + lw * EE, nullptr, nullptr, x, nullptr, EE, EE);
        ln_kernel<<<dim3(TT), dim3(256), 0, stream>>>(x, ln2g + lw * EE, ln2b + lw * EE, h_bf);
        gemm_bf16<2><<<dim3(FFD / 128, TT / 128), dim3(256), 0, stream>>>(
            h_bf, W1t, b1 + lw * FFD, nullptr, nullptr, nullptr, ffb, FFD, EE);
        gemm_bf16<1><<<dim3(EE / 128, TT / 128), dim3(256), 0, stream>>>(
            ffb, W2t, b2 + lw * EE, nullptr, nullptr, x, nullptr, EE, FFD);
    }

    ln_kernel<<<dim3(TT), dim3(256), 0, stream>>>(x, lnfg, lnfb, h_bf);
    pack_t_kernel<<<dim3(12, 48), dim3(256), 0, stream>>>(fw1, FFD, W1t, EE);
    pack_t_kernel<<<dim3(48, 12), dim3(256), 0, stream>>>(fw2, EE, W2t, FFD);
    gemm_bf16<2><<<dim3(FFD / 128, TT / 128), dim3(256), 0, stream>>>(
        h_bf, W1t, fb1, nullptr, nullptr, nullptr, ffb, FFD, EE);
    gemm_bf16<3><<<dim3(EE / 128, TT / 128), dim3(256), 0, stream>>>(
        ffb, W2t, fb2, nullptr, nullptr, x, nullptr, EE, FFD);
    head_kernel<<<dim3(TT), dim3(256), 0, stream>>>(x, hw, hb, out);
}

// Round 3
// 1547.557 us; speedup vs baseline: 1.3427x; 1.2681x over previous
//
#include <hip/hip_runtime.h>
#include <math.h>

#define TT 2048
#define EE 768
#define HNN 12
#define HSS 64
#define NLAYER 6
#define FFD 3072
#define QKVN 2304

constexpr float LN_EPS = 1e-5f;
constexpr float ATT_SCALE = 0.03608439182435161f; // 1/sqrt(768) (reference divides by sqrt(n_embed))

typedef __attribute__((ext_vector_type(8))) short bf16x8;
typedef __attribute__((ext_vector_type(4))) float f32x4;

__device__ __forceinline__ ushort f2bf(float f) {
    union { float f; uint u; } c; c.f = f;
    const uint u = c.u;
    return (ushort)((u + 0x7fffu + ((u >> 16) & 1u)) >> 16);
}

__device__ __forceinline__ void gload16(const void* g, void* l) {
    __builtin_amdgcn_global_load_lds((const __attribute__((address_space(1))) void*)g,
                                     (__attribute__((address_space(3))) void*)l, 16, 0, 0);
}

// ---------------------------------------------------------------- copy ----
__global__ __launch_bounds__(256) void copy4_kernel(float4* __restrict__ dst,
                                                    const float4* __restrict__ src, int n4) {
    int i = blockIdx.x * 256 + threadIdx.x;
    if (i < n4) dst[i] = src[i];
}

// ----------------------------------------------------------- layernorm ----
// one block (256 thr) per token; E=768 = 3*256.  fp32 in -> bf16 out.
__global__ __launch_bounds__(256) void ln_kernel(const float* __restrict__ in,
                                                 const float* __restrict__ g,
                                                 const float* __restrict__ b,
                                                 ushort* __restrict__ out) {
    __shared__ float red[8];
    const int t = blockIdx.x;
    const int tid = threadIdx.x;
    const float* row = in + (size_t)t * EE;
    float v0 = row[tid], v1 = row[tid + 256], v2 = row[tid + 512];
    float s = v0 + v1 + v2;
#pragma unroll
    for (int m = 1; m < 64; m <<= 1) s += __shfl_xor(s, m, 64);
    if ((tid & 63) == 0) red[tid >> 6] = s;
    __syncthreads();
    const float mean = (red[0] + red[1] + red[2] + red[3]) * (1.0f / EE);
    const float d0 = v0 - mean, d1 = v1 - mean, d2 = v2 - mean;
    float qq = d0 * d0 + d1 * d1 + d2 * d2;
#pragma unroll
    for (int m = 1; m < 64; m <<= 1) qq += __shfl_xor(qq, m, 64);
    __syncthreads();
    if ((tid & 63) == 0) red[tid >> 6] = qq;
    __syncthreads();
    const float var = (red[0] + red[1] + red[2] + red[3]) * (1.0f / EE);
    const float rstd = rsqrtf(var + LN_EPS);
    ushort* orow = out + (size_t)t * EE;
    orow[tid]       = f2bf(d0 * rstd * g[tid]       + b[tid]);
    orow[tid + 256] = f2bf(d1 * rstd * g[tid + 256] + b[tid + 256]);
    orow[tid + 512] = f2bf(d2 * rstd * g[tid + 512] + b[tid + 512]);
}

// --------------------------------------------------- weight pack (fp32->bf16^T)
// dst[n][k] (bf16, row stride dld) = src[k][n] (fp32, row stride sld), 64x64 tile
__device__ __forceinline__ void transpose64(const float* __restrict__ src, int sld,
                                            ushort* __restrict__ dst, int dld,
                                            int k0, int n0, int tid) {
    __shared__ float t[64][68];
#pragma unroll
    for (int p = 0; p < 4; p++) {
        const int kr = p * 16 + (tid >> 4);
        *(float4*)&t[kr][(tid & 15) * 4] =
            *(const float4*)&src[(size_t)(k0 + kr) * sld + n0 + (tid & 15) * 4];
    }
    __syncthreads();
#pragma unroll
    for (int q = 0; q < 2; q++) {
        const int nl = q * 32 + (tid >> 3);
        const int kc = (tid & 7) * 8;
        ushort v[8];
#pragma unroll
        for (int j = 0; j < 8; j++) v[j] = f2bf(t[kc + j][nl]);
        uint4 o;
        o.x = (uint)v[0] | ((uint)v[1] << 16);
        o.y = (uint)v[2] | ((uint)v[3] << 16);
        o.z = (uint)v[4] | ((uint)v[5] << 16);
        o.w = (uint)v[6] | ((uint)v[7] << 16);
        *(uint4*)&dst[(size_t)(n0 + nl) * dld + k0 + kc] = o;
    }
}

__global__ __launch_bounds__(256) void pack_t_kernel(const float* __restrict__ src, int sld,
                                                     ushort* __restrict__ dst, int dld) {
    transpose64(src, sld, dst, dld, blockIdx.x * 64, blockIdx.y * 64, threadIdx.x);
}

// qkv weights [HN][E][HS] (3 tensors) -> Wqkv_t[2304][768] bf16 (row n = which*768+h*64+s)
__global__ __launch_bounds__(256) void pack_qkv_kernel(const float* __restrict__ wq,
                                                       const float* __restrict__ wk,
                                                       const float* __restrict__ wv,
                                                       ushort* __restrict__ dst) {
    const int z = blockIdx.z;
    const int which = z / HNN, hd = z % HNN;
    const float* src = (which == 0 ? wq : which == 1 ? wk : wv) + (size_t)hd * EE * HSS;
    ushort* d = dst + (size_t)(which * EE + hd * HSS) * EE;
    transpose64(src, HSS, d, EE, blockIdx.x * 64, 0, threadIdx.x);
}

// ---------------------------------------------------------- bf16 GEMM ----
// C[M,N] = epi(A[M,K] @ Bt[N,K]^T + bias).  128x128 tile, BK=32, 4 waves
// each computing 64x64 via 4x4 grid of 16x16x32 bf16 MFMAs.
//
// R6 restructure (was: Occupancy 4%, FETCH 49MB vs 20MB ideal, loads drained
// before any MFMA):
//  - 1D grid + XCD-contiguous remap, mb fastest: each XCD owns a contiguous
//    chunk of (nb,ks) so its B working set (~0.6MB) + A (3MB) stays L2-resident.
//  - 2-phase pipelined K-loop: double-buffered LDS; per iter issue next-tile
//    global_load_lds BEFORE the MFMAs; single __syncthreads per iter (its
//    vmcnt(0) drain lands after compute -> load latency hidden).
//  - split-K (KS>1) for the 96-block shapes (proj/ff2): EPI=1 accumulates via
//    atomicAdd; bias added only by the ks==0 split.
//  - LDS swizzle (both-sides): global source colblk pre-permuted
//    ((lane&3)^((lane>>3)&3)), linear gload_lds dest, read col q4^((l15>>1)&3)
//    -> frag ds_read_b128 2-way banked (free) instead of 8-way.
// EPI: 0 = qkv (bf16 out, piecewise bias b0/b1/b2)
//      1 = accumulate into outF via atomicAdd (+bias if ks==0)
//      2 = gelu -> bf16 out
//      3 = plain fp32 out
template <int EPI>
__global__ __launch_bounds__(256) void gemm_bf16(const ushort* __restrict__ A,
                                                 const ushort* __restrict__ Bt,
                                                 const float* __restrict__ b0,
                                                 const float* __restrict__ b1,
                                                 const float* __restrict__ b2,
                                                 float* __restrict__ outF,
                                                 ushort* __restrict__ outB,
                                                 int N, int K,
                                                 int nby, int KS, int Kslice) {
    __shared__ ushort Al[2][128 * 32];
    __shared__ ushort Bl[2][128 * 32];
    const int tid = threadIdx.x;
    const int wave = tid >> 6, lane = tid & 63;
    const int wm = wave >> 1, wn = wave & 1;
    const int l15 = lane & 15, q4 = lane >> 4;

    // XCD-contiguous remap (all launches have gridDim.x % 8 == 0)
    const int nwg = gridDim.x;
    const int wgid = ((int)blockIdx.x & 7) * (nwg >> 3) + ((int)blockIdx.x >> 3);
    const int mb = wgid % nby;
    const int t2 = wgid / nby;
    const int ks = t2 % KS;
    const int nb = t2 / KS;
    const int m0 = mb * 128, n0 = nb * 128;
    const int kbase = ks * Kslice;

    // staging: lane -> row lane>>2, source colblk swizzled
    const int srow = lane >> 2;
    const int scb = (lane & 3) ^ ((lane >> 3) & 3);
    const ushort* Ag0 = A + (size_t)(m0 + wave * 16 + srow) * K + kbase + scb * 8;
    const ushort* Ag1 = Ag0 + (size_t)64 * K;
    const ushort* Bg0 = Bt + (size_t)(n0 + wave * 16 + srow) * K + kbase + scb * 8;
    const ushort* Bg1 = Bg0 + (size_t)64 * K;

    auto stage = [&](int buf, int kk) {
        const int off = kk * 32;
        gload16(Ag0 + off, &Al[buf][(wave * 16) * 32]);
        gload16(Ag1 + off, &Al[buf][(64 + wave * 16) * 32]);
        gload16(Bg0 + off, &Bl[buf][(wave * 16) * 32]);
        gload16(Bg1 + off, &Bl[buf][(64 + wave * 16) * 32]);
    };

    f32x4 acc[4][4];
#pragma unroll
    for (int i = 0; i < 4; i++)
#pragma unroll
        for (int j = 0; j < 4; j++) acc[i][j] = (f32x4){0.f, 0.f, 0.f, 0.f};

    stage(0, 0);
    __syncthreads();  // vmcnt(0) drain + barrier: tile 0 staged everywhere

    const int niter = Kslice >> 5;
    const int cq = (q4 ^ ((l15 >> 1) & 3)) * 8;  // swizzled read col (ushorts)

    for (int i = 0; i < niter; i++) {
        const int buf = i & 1;
        if (i + 1 < niter) stage(buf ^ 1, i + 1);  // in flight across the MFMAs
        bf16x8 af[4], bfr[4];
#pragma unroll
        for (int ii = 0; ii < 4; ii++)
            af[ii] = *(const bf16x8*)&Al[buf][(wm * 64 + ii * 16 + l15) * 32 + cq];
#pragma unroll
        for (int j = 0; j < 4; j++)
            bfr[j] = *(const bf16x8*)&Bl[buf][(wn * 64 + j * 16 + l15) * 32 + cq];
#pragma unroll
        for (int ii = 0; ii < 4; ii++)
#pragma unroll
            for (int j = 0; j < 4; j++)
                acc[ii][j] = __builtin_amdgcn_mfma_f32_16x16x32_bf16(af[ii], bfr[j], acc[ii][j], 0, 0, 0);
        __syncthreads();  // drains my vmcnt (next tile landed) + all waves done reading buf
    }

#pragma unroll
    for (int i = 0; i < 4; i++) {
        const int row = m0 + wm * 64 + i * 16 + q4 * 4;
#pragma unroll
        for (int j = 0; j < 4; j++) {
            const int col = n0 + wn * 64 + j * 16 + l15;
            float bias;
            if constexpr (EPI == 0)
                bias = (col < 768) ? b0[col] : (col < 1536 ? b1[col - 768] : b2[col - 1536]);
            else
                bias = (EPI == 1 && ks != 0) ? 0.f : b0[col];
#pragma unroll
            for (int r = 0; r < 4; r++) {
                const float v = acc[i][j][r] + bias;
                const size_t idx = (size_t)(row + r) * N + col;
                if constexpr (EPI == 0) {
                    outB[idx] = f2bf(v);
                } else if constexpr (EPI == 1) {
                    atomicAdd(&outF[idx], v);
                } else if constexpr (EPI == 2) {
                    outB[idx] = f2bf(0.5f * v * (1.0f + erff(v * 0.70710678118654752f)));
                } else {
                    outF[idx] = v;
                }
            }
        }
    }
}

// ----------------------------------------------------- MFMA attention ----
// flash-style causal attention, bf16 MFMA.  qkv [T][2304] bf16.
// One block per (64-q-tile, head); wave w owns q rows w*16..w*16+15.
// Swapped QK^T (lane holds 16 keys of one q-row), P via per-wave LDS
// round-trip (no barrier), double-buffered K/VT with register prefetch
// (one __syncthreads per iteration), XCD-aware head pinning.
__global__ __launch_bounds__(256) void attn_mfma(const ushort* __restrict__ qkv,
                                                 ushort* __restrict__ o_bf) {
    __shared__ __align__(16) ushort Ks[2][64 * 72];
    __shared__ __align__(16) ushort VT[2][64 * 72];  // V^T: [d][key ^ ((d>>3)<<3)]
    __shared__ __align__(16) uint   Ps[4][16 * 36];  // per-wave P rows (dwords)

    const int bid = blockIdx.x;
    const int x = bid & 7, r = bid >> 3;
    int hd, qt;
    if (r < 32) { hd = x;            qt = 31 - r; }
    else        { hd = 8 + (x & 3);  qt = (r - 32) * 2 + (x >> 2); }

    const int tid = threadIdx.x;
    const int wave = tid >> 6, lane = tid & 63;
    const int l15 = lane & 15, q4 = lane >> 4;
    const int rw = tid >> 3;      // 0..31: row within 32-row pass
    const int ch = tid & 7;       // 0..7: 16B chunk within 128B row

    // Q fragments (B-operand of swapped QK^T) -> registers, loaded once
    bf16x8 qa0, qa1;
    {
        const ushort* qrow = qkv + (size_t)(qt * 64 + wave * 16 + l15) * QKVN + hd * 64;
        qa0 = *(const bf16x8*)&qrow[q4 * 8];
        qa1 = *(const bf16x8*)&qrow[32 + q4 * 8];
    }

    const ushort* kg = qkv + 768 + hd * 64 + ch * 8;
    const ushort* vg = qkv + 1536 + hd * 64 + ch * 8;

    // stage kt=0 into buffer 0
#pragma unroll
    for (int p = 0; p < 2; p++) {
        const int row = rw + p * 32;
        const uint4 kv = *(const uint4*)&kg[(size_t)row * QKVN];
        *(uint4*)&Ks[0][row * 72 + ch * 8] = kv;
        const uint4 w = *(const uint4*)&vg[(size_t)row * QKVN];
        const int swz = row ^ (ch << 3);
        ushort* vt = &VT[0][(ch * 8) * 72 + swz];
        vt[0 * 72] = (ushort)(w.x & 0xffff);
        vt[1 * 72] = (ushort)(w.x >> 16);
        vt[2 * 72] = (ushort)(w.y & 0xffff);
        vt[3 * 72] = (ushort)(w.y >> 16);
        vt[4 * 72] = (ushort)(w.z & 0xffff);
        vt[5 * 72] = (ushort)(w.z >> 16);
        vt[6 * 72] = (ushort)(w.w & 0xffff);
        vt[7 * 72] = (ushort)(w.w >> 16);
    }
    __syncthreads();

    float m_i = -1e30f;   // running max for q-row (wave*16 + l15)
    float l_i = 0.f;      // running sum for q-row (wave*16 + l15)
    f32x4 oacc[4];
#pragma unroll
    for (int n = 0; n < 4; n++) oacc[n] = (f32x4){0.f, 0.f, 0.f, 0.f};

    for (int kt = 0; kt <= qt; kt++) {
        const int buf = kt & 1;
        const bool more = (kt < qt);
        uint4 knxt[2], vnxt[2];
        if (more) {
#pragma unroll
            for (int p = 0; p < 2; p++) {
                knxt[p] = *(const uint4*)&kg[(size_t)((kt + 1) * 64 + rw + p * 32) * QKVN];
                vnxt[p] = *(const uint4*)&vg[(size_t)((kt + 1) * 64 + rw + p * 32) * QKVN];
            }
        }

        // S^T = K Q^T : lane -> q-row (wave*16+l15), keys n*16+q4*4+r
        const ushort* Kb = &Ks[buf][0];
        f32x4 s[4];
#pragma unroll
        for (int n = 0; n < 4; n++) {
            const bf16x8 kf0 = *(const bf16x8*)&Kb[(n * 16 + l15) * 72 + q4 * 8];
            const bf16x8 kf1 = *(const bf16x8*)&Kb[(n * 16 + l15) * 72 + 32 + q4 * 8];
            f32x4 a = (f32x4){0.f, 0.f, 0.f, 0.f};
            a = __builtin_amdgcn_mfma_f32_16x16x32_bf16(kf0, qa0, a, 0, 0, 0);
            a = __builtin_amdgcn_mfma_f32_16x16x32_bf16(kf1, qa1, a, 0, 0, 0);
            s[n] = a;
        }

        const bool diag = (kt == qt);
        const int qrl = wave * 16 + l15;
        float pe[16];
        float mx = -1e30f;
#pragma unroll
        for (int n = 0; n < 4; n++)
#pragma unroll
            for (int rr = 0; rr < 4; rr++) {
                float xv = s[n][rr] * ATT_SCALE;
                if (diag && (n * 16 + q4 * 4 + rr) > qrl) xv = -1e30f;
                pe[n * 4 + rr] = xv;
                mx = fmaxf(mx, xv);
            }
        mx = fmaxf(mx, __shfl_xor(mx, 16, 64));
        mx = fmaxf(mx, __shfl_xor(mx, 32, 64));
        const float nm = fmaxf(m_i, mx);
        const float al = __expf(m_i - nm);
        float rs = 0.f;
#pragma unroll
        for (int i = 0; i < 16; i++) {
            pe[i] = __expf(pe[i] - nm);
            rs += pe[i];
        }
        rs += __shfl_xor(rs, 16, 64);
        rs += __shfl_xor(rs, 32, 64);
        l_i = l_i * al + rs;
        m_i = nm;

        // alpha for O-rows q4*4+rr (O acc layout) from per-q-row lanes
        float alr[4];
#pragma unroll
        for (int rr = 0; rr < 4; rr++) alr[rr] = __shfl(al, q4 * 4 + rr, 64);
#pragma unroll
        for (int n = 0; n < 4; n++) {
            oacc[n][0] *= alr[0];
            oacc[n][1] *= alr[1];
            oacc[n][2] *= alr[2];
            oacc[n][3] *= alr[3];
        }

        // P -> per-wave LDS (packed b64 writes, swizzled) -> A-fragments.
        // Intra-wave round trip: no barrier (compiler lgkm ordering).
        uint* psrow = &Ps[wave][l15 * 36];
        const int psx = (l15 & 7) << 2;
#pragma unroll
        for (int n = 0; n < 4; n++) {
            uint2 d;
            d.x = (uint)f2bf(pe[n * 4 + 0]) | ((uint)f2bf(pe[n * 4 + 1]) << 16);
            d.y = (uint)f2bf(pe[n * 4 + 2]) | ((uint)f2bf(pe[n * 4 + 3]) << 16);
            *(uint2*)&psrow[(n * 8 + q4 * 2) ^ psx] = d;
        }
        const bf16x8 pa0 = *(const bf16x8*)&psrow[(q4 * 4) ^ psx];
        const bf16x8 pa1 = *(const bf16x8*)&psrow[(16 + q4 * 4) ^ psx];

        // O += P V   (4 d-tiles of 16)
        const ushort* Vb = &VT[buf][0];
#pragma unroll
        for (int n = 0; n < 4; n++) {
            const int drow = n * 16 + l15;
            const int vsw = ((drow >> 3) & 7) << 3;
            const bf16x8 vb0 = *(const bf16x8*)&Vb[drow * 72 + ((q4 * 8) ^ vsw)];
            const bf16x8 vb1 = *(const bf16x8*)&Vb[drow * 72 + ((32 + q4 * 8) ^ vsw)];
            oacc[n] = __builtin_amdgcn_mfma_f32_16x16x32_bf16(pa0, vb0, oacc[n], 0, 0, 0);
            oacc[n] = __builtin_amdgcn_mfma_f32_16x16x32_bf16(pa1, vb1, oacc[n], 0, 0, 0);
        }

        // stage kt+1 into the other buffer (loads were in flight all iter)
        if (more) {
#pragma unroll
            for (int p = 0; p < 2; p++) {
                const int row = rw + p * 32;
                *(uint4*)&Ks[buf ^ 1][row * 72 + ch * 8] = knxt[p];
                const uint4 w = vnxt[p];
                const int swz = row ^ (ch << 3);
                ushort* vt = &VT[buf ^ 1][(ch * 8) * 72 + swz];
                vt[0 * 72] = (ushort)(w.x & 0xffff);
                vt[1 * 72] = (ushort)(w.x >> 16);
                vt[2 * 72] = (ushort)(w.y & 0xffff);
                vt[3 * 72] = (ushort)(w.y >> 16);
                vt[4 * 72] = (ushort)(w.z & 0xffff);
                vt[5 * 72] = (ushort)(w.z >> 16);
                vt[6 * 72] = (ushort)(w.w & 0xffff);
                vt[7 * 72] = (ushort)(w.w >> 16);
            }
        }
        __syncthreads();
    }

    float lrec[4];
#pragma unroll
    for (int rr = 0; rr < 4; rr++) lrec[rr] = 1.0f / __shfl(l_i, q4 * 4 + rr, 64);
#pragma unroll
    for (int n = 0; n < 4; n++)
#pragma unroll
        for (int rr = 0; rr < 4; rr++)
            o_bf[(size_t)(qt * 64 + wave * 16 + q4 * 4 + rr) * EE + hd * 64 + n * 16 + l15] =
                f2bf(oacc[n][rr] * lrec[rr]);
}

// ---------------------------------------------------------------- head ----
__global__ __launch_bounds__(256) void head_kernel(const float* __restrict__ x,
                                                   const float* __restrict__ hw,
                                                   const float* __restrict__ hb,
                                                   float* __restrict__ out) {
    __shared__ float red[8];
    const int t = blockIdx.x, tid = threadIdx.x;
    const float* row = x + (size_t)t * EE;
    float s = row[tid] * hw[tid] + row[tid + 256] * hw[tid + 256] + row[tid + 512] * hw[tid + 512];
#pragma unroll
    for (int m = 1; m < 64; m <<= 1) s += __shfl_xor(s, m, 64);
    if ((tid & 63) == 0) red[tid >> 6] = s;
    __syncthreads();
    if (tid == 0) out[t] = red[0] + red[1] + red[2] + red[3] + hb[0];
}

// -------------------------------------------------------------- launch ----
extern "C" void kernel_launch(void* const* d_in, const int* in_sizes, int n_in,
                              void* d_out, int out_size, void* d_ws, size_t ws_size,
                              hipStream_t stream) {
    const float* idx   = (const float*)d_in[0];
    const float* wq    = (const float*)d_in[2];
    const float* bq    = (const float*)d_in[3];
    const float* wk    = (const float*)d_in[4];
    const float* bk    = (const float*)d_in[5];
    const float* wv    = (const float*)d_in[6];
    const float* bv    = (const float*)d_in[7];
    const float* wproj = (const float*)d_in[8];
    const float* bproj = (const float*)d_in[9];
    const float* ln1g  = (const float*)d_in[10];
    const float* ln1b  = (const float*)d_in[11];
    const float* ln2g  = (const float*)d_in[12];
    const float* ln2b  = (const float*)d_in[13];
    const float* w1    = (const float*)d_in[14];
    const float* b1    = (const float*)d_in[15];
    const float* w2    = (const float*)d_in[16];
    const float* b2    = (const float*)d_in[17];
    const float* lnfg  = (const float*)d_in[18];
    const float* lnfb  = (const float*)d_in[19];
    const float* fw1   = (const float*)d_in[20];
    const float* fb1   = (const float*)d_in[21];
    const float* fw2   = (const float*)d_in[22];
    const float* fb2   = (const float*)d_in[23];
    const float* hw    = (const float*)d_in[24];
    const float* hb    = (const float*)d_in[25];
    float* out = (float*)d_out;

    // ---- workspace carve (~47 MB) ----
    char* p = (char*)d_ws;
    auto alloc = [&](size_t bytes) { void* r = (void*)p; p += (bytes + 255) & ~(size_t)255; return r; };
    float*  x     = (float*)alloc((size_t)TT * EE * 4);
    ushort* h_bf  = (ushort*)alloc((size_t)TT * EE * 2);
    ushort* qkvb  = (ushort*)alloc((size_t)TT * QKVN * 2);
    ushort* o_bf  = (ushort*)alloc((size_t)TT * EE * 2);
    ushort* ffb   = (ushort*)alloc((size_t)TT * FFD * 2);
    ushort* Wqkv  = (ushort*)alloc((size_t)QKVN * EE * 2);
    ushort* Wproj = (ushort*)alloc((size_t)EE * EE * 2);
    ushort* W1t   = (ushort*)alloc((size_t)FFD * EE * 2);
    ushort* W2t   = (ushort*)alloc((size_t)EE * FFD * 2);

    // only batch 3 contributes to the output (logits[-1]; no cross-batch mixing)
    copy4_kernel<<<dim3((TT * EE / 4 + 255) / 256), dim3(256), 0, stream>>>(
        (float4*)x, (const float4*)(idx + (size_t)3 * TT * EE), TT * EE / 4);

    for (int l = 0; l < NLAYER; l++) {
        const size_t lw = (size_t)l;
        pack_qkv_kernel<<<dim3(12, 1, 36), dim3(256), 0, stream>>>(
            wq + lw * HNN * EE * HSS, wk + lw * HNN * EE * HSS, wv + lw * HNN * EE * HSS, Wqkv);
        pack_t_kernel<<<dim3(12, 12), dim3(256), 0, stream>>>(wproj + lw * EE * EE, EE, Wproj, EE);
        pack_t_kernel<<<dim3(12, 48), dim3(256), 0, stream>>>(w1 + lw * EE * FFD, FFD, W1t, EE);
        pack_t_kernel<<<dim3(48, 12), dim3(256), 0, stream>>>(w2 + lw * FFD * EE, EE, W2t, FFD);

        ln_kernel<<<dim3(TT), dim3(256), 0, stream>>>(x, ln1g + lw * EE, ln1b + lw * EE, h_bf);
        // QKV: 18x16 = 288 blocks
        gemm_bf16<0><<<dim3(288), dim3(256), 0, stream>>>(
            h_bf, Wqkv, bq + lw * EE, bk + lw * EE, bv + lw * EE, nullptr, qkvb,
            QKVN, EE, 16, 1, EE);
        attn_mfma<<<dim3(384), dim3(256), 0, stream>>>(qkvb, o_bf);
        // proj: 6x16, split-K x4 (Kslice 192) -> 384 blocks, atomic accum into x
        gemm_bf16<1><<<dim3(384), dim3(256), 0, stream>>>(
            o_bf, Wproj, bproj + lw * EE, nullptr, nullptr, x, nullptr,
            EE, EE, 16, 4, 192);
        ln_kernel<<<dim3(TT), dim3(256), 0, stream>>>(x, ln2g + lw * EE, ln2b + lw * EE, h_bf);
        // FF1: 24x16 = 384 blocks
        gemm_bf16<2><<<dim3(384), dim3(256), 0, stream>>>(
            h_bf, W1t, b1 + lw * FFD, nullptr, nullptr, nullptr, ffb,
            FFD, EE, 16, 1, EE);
        // FF2: 6x16, split-K x4 (Kslice 768) -> 384 blocks, atomic accum into x
        gemm_bf16<1><<<dim3(384), dim3(256), 0, stream>>>(
            ffb, W2t, b2 + lw * EE, nullptr, nullptr, x, nullptr,
            EE, FFD, 16, 4, 768);
    }

    ln_kernel<<<dim3(TT), dim3(256), 0, stream>>>(x, lnfg, lnfb, h_bf);
    pack_t_kernel<<<dim3(12, 48), dim3(256), 0, stream>>>(fw1, FFD, W1t, EE);
    pack_t_kernel<<<dim3(48, 12), dim3(256), 0, stream>>>(fw2, EE, W2t, FFD);
    gemm_bf16<2><<<dim3(384), dim3(256), 0, stream>>>(
        h_bf, W1t, fb1, nullptr, nullptr, nullptr, ffb, FFD, EE, 16, 1, EE);
    gemm_bf16<3><<<dim3(96), dim3(256), 0, stream>>>(
        ffb, W2t, fb2, nullptr, nullptr, x, nullptr, EE, FFD, 16, 1, FFD);
    head_kernel<<<dim3(TT), dim3(256), 0, stream>>>(x, hw, hb, out);
}